// Round 1
// baseline (616.435 us; speedup 1.0000x reference)
//
#include <hip/hip_runtime.h>
#include <math.h>

#define BB 16
#define GG 512
#define PP 512
#define EE 256
#define HH 16
#define KD 16
#define HK 256

// ---------------------------------------------------------------------------
// Generic tiled fp32 GEMM: C[M,N] = A[M,Kd] @ B[Kd,N] (+ optional bias[N])
// BM=BN=64, BK=16, 256 threads, 4x4 micro-tile per thread.
// Requires M%64==0, N%64==0, Kd%16==0.
// ---------------------------------------------------------------------------
__global__ __launch_bounds__(256) void gemm64(const float* __restrict__ A,
                                              const float* __restrict__ Bm,
                                              const float* __restrict__ bias,
                                              float* __restrict__ C,
                                              int M, int N, int Kd)
{
    __shared__ float As[64][17];
    __shared__ float Bs[16][68];
    const int tid = threadIdx.x;
    const int tr = tid >> 4, tc = tid & 15;
    const int m0 = blockIdx.y * 64, n0 = blockIdx.x * 64;
    const int ar = tid >> 2, ac = (tid & 3) << 2;   // A-tile load coords (64x16)
    const int br = tid >> 4, bc = (tid & 15) << 2;  // B-tile load coords (16x64)

    float acc[4][4] = {};

    for (int k0 = 0; k0 < Kd; k0 += 16) {
        float4 a4 = *(const float4*)(A + (size_t)(m0 + ar) * Kd + k0 + ac);
        float4 b4 = *(const float4*)(Bm + (size_t)(k0 + br) * N + n0 + bc);
        As[ar][ac + 0] = a4.x; As[ar][ac + 1] = a4.y;
        As[ar][ac + 2] = a4.z; As[ar][ac + 3] = a4.w;
        Bs[br][bc + 0] = b4.x; Bs[br][bc + 1] = b4.y;
        Bs[br][bc + 2] = b4.z; Bs[br][bc + 3] = b4.w;
        __syncthreads();
#pragma unroll
        for (int kk = 0; kk < 16; ++kk) {
            float a[4], b[4];
#pragma unroll
            for (int r = 0; r < 4; ++r) a[r] = As[tr * 4 + r][kk];
#pragma unroll
            for (int c = 0; c < 4; ++c) b[c] = Bs[kk][tc * 4 + c];
#pragma unroll
            for (int r = 0; r < 4; ++r)
#pragma unroll
                for (int c = 0; c < 4; ++c) acc[r][c] += a[r] * b[c];
        }
        __syncthreads();
    }

#pragma unroll
    for (int r = 0; r < 4; ++r) {
        const int m = m0 + tr * 4 + r;
#pragma unroll
        for (int c = 0; c < 4; ++c) {
            const int n = n0 + tc * 4 + c;
            float v = acc[r][c];
            if (bias) v += bias[n];
            C[(size_t)m * N + n] = v;
        }
    }
}

// ---------------------------------------------------------------------------
// Q projection: q = concat(bcast(input1), input2, current_time) @ Wq
// Implemented as K=512 virtual-A GEMM + rank-1 current_time x Wq[512,:].
// M = B*G = 8192, N = 256. Wq is [513, 256].
// ---------------------------------------------------------------------------
__global__ __launch_bounds__(256) void qgemm(const float* __restrict__ in1,
                                             const float* __restrict__ in2,
                                             const float* __restrict__ ct,
                                             const float* __restrict__ Wq,
                                             float* __restrict__ Qm)
{
    __shared__ float As[64][17];
    __shared__ float Bs[16][68];
    const int tid = threadIdx.x;
    const int tr = tid >> 4, tc = tid & 15;
    const int m0 = blockIdx.y * 64, n0 = blockIdx.x * 64;
    const int b = m0 >> 9;  // 64-row tiles never straddle a batch boundary (G=512)
    const int ar = tid >> 2, ac = (tid & 3) << 2;
    const int br = tid >> 4, bc = (tid & 15) << 2;

    float acc[4][4] = {};

    for (int k0 = 0; k0 < 512; k0 += 16) {
        float4 a4;
        if (k0 < 256) {
            // broadcast input1 row of batch b (same for every m in tile)
            a4 = *(const float4*)(in1 + (size_t)b * EE + k0 + ac);
        } else {
            a4 = *(const float4*)(in2 + (size_t)(m0 + ar) * EE + (k0 - 256) + ac);
        }
        float4 b4 = *(const float4*)(Wq + (size_t)(k0 + br) * HK + n0 + bc);
        As[ar][ac + 0] = a4.x; As[ar][ac + 1] = a4.y;
        As[ar][ac + 2] = a4.z; As[ar][ac + 3] = a4.w;
        Bs[br][bc + 0] = b4.x; Bs[br][bc + 1] = b4.y;
        Bs[br][bc + 2] = b4.z; Bs[br][bc + 3] = b4.w;
        __syncthreads();
#pragma unroll
        for (int kk = 0; kk < 16; ++kk) {
            float a[4], b[4];
#pragma unroll
            for (int r = 0; r < 4; ++r) a[r] = As[tr * 4 + r][kk];
#pragma unroll
            for (int c = 0; c < 4; ++c) b[c] = Bs[kk][tc * 4 + c];
#pragma unroll
            for (int r = 0; r < 4; ++r)
#pragma unroll
                for (int c = 0; c < 4; ++c) acc[r][c] += a[r] * b[c];
        }
        __syncthreads();
    }

    // rank-1 epilogue: + current_time[m] * Wq[512, n]
#pragma unroll
    for (int r = 0; r < 4; ++r) {
        const int m = m0 + tr * 4 + r;
        const float t = ct[m];
#pragma unroll
        for (int c = 0; c < 4; ++c) {
            const int n = n0 + tc * 4 + c;
            Qm[(size_t)m * HK + n] = acc[r][c] + t * Wq[(size_t)512 * HK + n];
        }
    }
}

// ---------------------------------------------------------------------------
// MHA: one block = (b, h, 16 g's). scores in LDS, shuffle softmax, PV.
// Q/K/V stored as [B*{G|P}, 256] with head slice h*16..h*16+15.
// ---------------------------------------------------------------------------
__global__ __launch_bounds__(256) void attn_kernel(const float* __restrict__ Qm,
                                                   const float* __restrict__ Km,
                                                   const float* __restrict__ Vm,
                                                   const float* __restrict__ mask,
                                                   float* __restrict__ Out)
{
    __shared__ float sQ[16][17];
    __shared__ float sS[16][516];
    const int t = threadIdx.x;
    const int b = blockIdx.z, h = blockIdx.y, g0 = blockIdx.x * 16;

    // load q fragments: thread t -> (g=t>>4, k=t&15)
    sQ[t >> 4][t & 15] =
        Qm[(size_t)(b * GG + g0 + (t >> 4)) * HK + h * KD + (t & 15)];
    __syncthreads();

    // phase 1: scores. thread t -> g = t&15 (fixed), p = (t>>4) + 16*i
    {
        const int g = t & 15;
        float qreg[16];
#pragma unroll
        for (int k = 0; k < 16; ++k) qreg[k] = sQ[g][k];
        const float* Kb = Km + (size_t)b * PP * HK + h * KD;
#pragma unroll 2
        for (int i = 0; i < 32; ++i) {
            const int p = (i << 4) + (t >> 4);
            const float4* kr = (const float4*)(Kb + (size_t)p * HK);
            float4 k0 = kr[0], k1 = kr[1], k2 = kr[2], k3 = kr[3];
            float d = qreg[0] * k0.x + qreg[1] * k0.y + qreg[2] * k0.z + qreg[3] * k0.w
                    + qreg[4] * k1.x + qreg[5] * k1.y + qreg[6] * k1.z + qreg[7] * k1.w
                    + qreg[8] * k2.x + qreg[9] * k2.y + qreg[10] * k2.z + qreg[11] * k2.w
                    + qreg[12] * k3.x + qreg[13] * k3.y + qreg[14] * k3.z + qreg[15] * k3.w;
            sS[g][p] = d * 0.25f;  // 1/sqrt(16)
        }
    }
    __syncthreads();

    // phase 2: masked softmax per g-row; 16 lanes per row.
    const int g = t >> 4, j = t & 15;
    const float* mrow = mask + (size_t)(b * GG + g0 + g) * PP;
    float mx = -1e30f;
#pragma unroll 4
    for (int ii = 0; ii < 32; ++ii) {
        const int p = j + (ii << 4);
        const float s = sS[g][p] + mrow[p];
        sS[g][p] = s;
        mx = fmaxf(mx, s);
    }
#pragma unroll
    for (int mbit = 1; mbit < 16; mbit <<= 1) mx = fmaxf(mx, __shfl_xor(mx, mbit));
    float sum = 0.f;
#pragma unroll 4
    for (int ii = 0; ii < 32; ++ii) {
        const int p = j + (ii << 4);
        const float e = __expf(sS[g][p] - mx);
        sS[g][p] = e;
        sum += e;
    }
#pragma unroll
    for (int mbit = 1; mbit < 16; mbit <<= 1) sum += __shfl_xor(sum, mbit);
    const float inv = 1.f / sum;
    __syncthreads();

    // phase 3: out[g][k] = inv * sum_p w[g][p] * V[b,p,h*16+k]; same g as phase 2.
    {
        const int k = t & 15;
        const float* Vb = Vm + (size_t)b * PP * HK + h * KD + k;
        float acc = 0.f;
#pragma unroll 8
        for (int p = 0; p < PP; ++p) acc += sS[g][p] * Vb[(size_t)p * HK];
        Out[(size_t)(b * GG + g0 + g) * HK + h * KD + k] = acc * inv;
    }
}

// ---------------------------------------------------------------------------
// Pointer head: score2 = mh @ enc^T / 16 -> 10*tanh -> +mask -> softmax.
// One block = (b, 16 g's). 256 threads.
// ---------------------------------------------------------------------------
__global__ __launch_bounds__(256) void pointer_probs(const float* __restrict__ mh,
                                                     const float* __restrict__ enc,
                                                     const float* __restrict__ mask,
                                                     float* __restrict__ out)
{
    __shared__ float sM[16][260];
    __shared__ float sS[16][516];
    const int t = threadIdx.x;
    const int b = blockIdx.y, g0 = blockIdx.x * 16;

    // load mh tile (16 x 256)
    {
        const int r = t >> 4;
#pragma unroll
        for (int i = 0; i < 4; ++i) {
            const int c = ((t & 15) << 2) + (i << 6);
            float4 v = *(const float4*)(mh + (size_t)(b * GG + g0 + r) * EE + c);
            sM[r][c + 0] = v.x; sM[r][c + 1] = v.y;
            sM[r][c + 2] = v.z; sM[r][c + 3] = v.w;
        }
    }
    __syncthreads();

    // phase 1: dot-256 scores, 4 p's per pass to amortize LDS reads of q.
    {
        const int g = t & 15;
        const float4* qr = (const float4*)(&sM[g][0]);
        const float* Eb = enc + (size_t)b * PP * EE;
        for (int i4 = 0; i4 < 8; ++i4) {
            const int pb = (t >> 4) + (i4 << 6);
            const float4* e0 = (const float4*)(Eb + (size_t)(pb +  0) * EE);
            const float4* e1 = (const float4*)(Eb + (size_t)(pb + 16) * EE);
            const float4* e2 = (const float4*)(Eb + (size_t)(pb + 32) * EE);
            const float4* e3 = (const float4*)(Eb + (size_t)(pb + 48) * EE);
            float d0 = 0.f, d1 = 0.f, d2 = 0.f, d3 = 0.f;
#pragma unroll 8
            for (int e4 = 0; e4 < 64; ++e4) {
                const float4 qv = qr[e4];
                const float4 a = e0[e4], bb = e1[e4], cc = e2[e4], dd = e3[e4];
                d0 += qv.x * a.x + qv.y * a.y + qv.z * a.z + qv.w * a.w;
                d1 += qv.x * bb.x + qv.y * bb.y + qv.z * bb.z + qv.w * bb.w;
                d2 += qv.x * cc.x + qv.y * cc.y + qv.z * cc.z + qv.w * cc.w;
                d3 += qv.x * dd.x + qv.y * dd.y + qv.z * dd.z + qv.w * dd.w;
            }
            sS[g][pb +  0] = d0 * 0.0625f;  // 1/sqrt(256)
            sS[g][pb + 16] = d1 * 0.0625f;
            sS[g][pb + 32] = d2 * 0.0625f;
            sS[g][pb + 48] = d3 * 0.0625f;
        }
    }
    __syncthreads();

    // phase 2: clip + mask + softmax + store. 16 lanes per g-row.
    const int g = t >> 4, j = t & 15;
    const float* mrow = mask + (size_t)(b * GG + g0 + g) * PP;
    float mx = -1e30f;
#pragma unroll 4
    for (int ii = 0; ii < 32; ++ii) {
        const int p = j + (ii << 4);
        const float s = 10.f * tanhf(sS[g][p]) + mrow[p];
        sS[g][p] = s;
        mx = fmaxf(mx, s);
    }
#pragma unroll
    for (int mbit = 1; mbit < 16; mbit <<= 1) mx = fmaxf(mx, __shfl_xor(mx, mbit));
    float sum = 0.f;
#pragma unroll 4
    for (int ii = 0; ii < 32; ++ii) {
        const int p = j + (ii << 4);
        const float e = __expf(sS[g][p] - mx);
        sS[g][p] = e;
        sum += e;
    }
#pragma unroll
    for (int mbit = 1; mbit < 16; mbit <<= 1) sum += __shfl_xor(sum, mbit);
    const float inv = 1.f / sum;
    float* orow = out + (size_t)(b * GG + g0 + g) * PP;
#pragma unroll 4
    for (int ii = 0; ii < 32; ++ii) {
        const int p = j + (ii << 4);
        orow[p] = sS[g][p] * inv;
    }
}

// ---------------------------------------------------------------------------
extern "C" void kernel_launch(void* const* d_in, const int* in_sizes, int n_in,
                              void* d_out, int out_size, void* d_ws, size_t ws_size,
                              hipStream_t stream)
{
    const float* in1  = (const float*)d_in[0];  // [B,1,E]
    const float* in2  = (const float*)d_in[1];  // [B,G,E]
    const float* ct   = (const float*)d_in[2];  // [B,G,1]
    const float* mask = (const float*)d_in[3];  // [B,G,P]
    const float* enc  = (const float*)d_in[4];  // [B,P,E]
    const float* Wq   = (const float*)d_in[5];  // [513, 256]
    const float* Wk   = (const float*)d_in[6];  // [256, 256]
    const float* Wv   = (const float*)d_in[7];  // [256, 256]
    const float* Wcw  = (const float*)d_in[8];  // [256, 256]
    const float* Wcb  = (const float*)d_in[9];  // [256]
    float* out = (float*)d_out;
    float* ws  = (float*)d_ws;

    const size_t SEG = (size_t)BB * GG * HK;  // 2,097,152 floats = 8 MB
    float* Kmat = ws;
    float* Vmat = ws + SEG;
    float* Qmat = ws + 2 * SEG;
    float* Att  = ws + 3 * SEG;
    float* mhv  = ws;  // reuse Kmat region (K no longer needed after attention)

    const dim3 blk(256);
    const int M = BB * GG;  // 8192

    gemm64<<<dim3(HK / 64, M / 64), blk, 0, stream>>>(enc, Wk, nullptr, Kmat, M, HK, EE);
    gemm64<<<dim3(HK / 64, M / 64), blk, 0, stream>>>(enc, Wv, nullptr, Vmat, M, HK, EE);
    qgemm <<<dim3(HK / 64, M / 64), blk, 0, stream>>>(in1, in2, ct, Wq, Qmat);
    attn_kernel<<<dim3(GG / 16, HH, BB), blk, 0, stream>>>(Qmat, Kmat, Vmat, mask, Att);
    gemm64<<<dim3(HK / 64, M / 64), blk, 0, stream>>>(Att, Wcw, Wcb, mhv, M, HK, EE);
    pointer_probs<<<dim3(GG / 16, BB), blk, 0, stream>>>(mhv, enc, mask, out);
}

// Round 2
// 470.941 us; speedup vs baseline: 1.3089x; 1.3089x over previous
//
#include <hip/hip_runtime.h>
#include <math.h>

#define BB 16
#define GG 512
#define PP 512
#define EE 256
#define HH 16
#define KD 16
#define HK 256

// ---------------------------------------------------------------------------
// Generic tiled fp32 GEMM: C[M,N] = A[M,Kd] @ B[Kd,N] (+ optional bias[N])
// BM=BN=64, BK=16, 256 threads, 4x4 micro-tile per thread.
// ---------------------------------------------------------------------------
__global__ __launch_bounds__(256) void gemm64(const float* __restrict__ A,
                                              const float* __restrict__ Bm,
                                              const float* __restrict__ bias,
                                              float* __restrict__ C,
                                              int M, int N, int Kd)
{
    __shared__ float As[64][17];
    __shared__ float Bs[16][68];
    const int tid = threadIdx.x;
    const int tr = tid >> 4, tc = tid & 15;
    const int m0 = blockIdx.y * 64, n0 = blockIdx.x * 64;
    const int ar = tid >> 2, ac = (tid & 3) << 2;
    const int br = tid >> 4, bc = (tid & 15) << 2;

    float acc[4][4] = {};

    for (int k0 = 0; k0 < Kd; k0 += 16) {
        float4 a4 = *(const float4*)(A + (size_t)(m0 + ar) * Kd + k0 + ac);
        float4 b4 = *(const float4*)(Bm + (size_t)(k0 + br) * N + n0 + bc);
        As[ar][ac + 0] = a4.x; As[ar][ac + 1] = a4.y;
        As[ar][ac + 2] = a4.z; As[ar][ac + 3] = a4.w;
        Bs[br][bc + 0] = b4.x; Bs[br][bc + 1] = b4.y;
        Bs[br][bc + 2] = b4.z; Bs[br][bc + 3] = b4.w;
        __syncthreads();
#pragma unroll
        for (int kk = 0; kk < 16; ++kk) {
            float a[4], b[4];
#pragma unroll
            for (int r = 0; r < 4; ++r) a[r] = As[tr * 4 + r][kk];
#pragma unroll
            for (int c = 0; c < 4; ++c) b[c] = Bs[kk][tc * 4 + c];
#pragma unroll
            for (int r = 0; r < 4; ++r)
#pragma unroll
                for (int c = 0; c < 4; ++c) acc[r][c] += a[r] * b[c];
        }
        __syncthreads();
    }

#pragma unroll
    for (int r = 0; r < 4; ++r) {
        const int m = m0 + tr * 4 + r;
#pragma unroll
        for (int c = 0; c < 4; ++c) {
            const int n = n0 + tc * 4 + c;
            float v = acc[r][c];
            if (bias) v += bias[n];
            C[(size_t)m * N + n] = v;
        }
    }
}

// ---------------------------------------------------------------------------
// Projection GEMM with head-major epilogue: C'[b,h,p,k] layout for K/V so the
// attention kernel can read rows with wave-uniform (scalar) loads.
// ---------------------------------------------------------------------------
__global__ __launch_bounds__(256) void gemm64_perm(const float* __restrict__ A,
                                                   const float* __restrict__ Bm,
                                                   float* __restrict__ C,
                                                   int M, int N, int Kd)
{
    __shared__ float As[64][17];
    __shared__ float Bs[16][68];
    const int tid = threadIdx.x;
    const int tr = tid >> 4, tc = tid & 15;
    const int m0 = blockIdx.y * 64, n0 = blockIdx.x * 64;
    const int ar = tid >> 2, ac = (tid & 3) << 2;
    const int br = tid >> 4, bc = (tid & 15) << 2;

    float acc[4][4] = {};

    for (int k0 = 0; k0 < Kd; k0 += 16) {
        float4 a4 = *(const float4*)(A + (size_t)(m0 + ar) * Kd + k0 + ac);
        float4 b4 = *(const float4*)(Bm + (size_t)(k0 + br) * N + n0 + bc);
        As[ar][ac + 0] = a4.x; As[ar][ac + 1] = a4.y;
        As[ar][ac + 2] = a4.z; As[ar][ac + 3] = a4.w;
        Bs[br][bc + 0] = b4.x; Bs[br][bc + 1] = b4.y;
        Bs[br][bc + 2] = b4.z; Bs[br][bc + 3] = b4.w;
        __syncthreads();
#pragma unroll
        for (int kk = 0; kk < 16; ++kk) {
            float a[4], b[4];
#pragma unroll
            for (int r = 0; r < 4; ++r) a[r] = As[tr * 4 + r][kk];
#pragma unroll
            for (int c = 0; c < 4; ++c) b[c] = Bs[kk][tc * 4 + c];
#pragma unroll
            for (int r = 0; r < 4; ++r)
#pragma unroll
                for (int c = 0; c < 4; ++c) acc[r][c] += a[r] * b[c];
        }
        __syncthreads();
    }

#pragma unroll
    for (int r = 0; r < 4; ++r) {
        const int m = m0 + tr * 4 + r;
        const int b = m >> 9, p = m & (PP - 1);
#pragma unroll
        for (int c = 0; c < 4; ++c) {
            const int n = n0 + tc * 4 + c;
            const int h = n >> 4, k = n & 15;
            C[(((size_t)b * HH + h) * PP + p) * KD + k] = acc[r][c];
        }
    }
}

// ---------------------------------------------------------------------------
// Q projection with head-major epilogue: Q'[b,h,g,k].
// ---------------------------------------------------------------------------
__global__ __launch_bounds__(256) void qgemm(const float* __restrict__ in1,
                                             const float* __restrict__ in2,
                                             const float* __restrict__ ct,
                                             const float* __restrict__ Wq,
                                             float* __restrict__ Qm)
{
    __shared__ float As[64][17];
    __shared__ float Bs[16][68];
    const int tid = threadIdx.x;
    const int tr = tid >> 4, tc = tid & 15;
    const int m0 = blockIdx.y * 64, n0 = blockIdx.x * 64;
    const int bidx = m0 >> 9;
    const int ar = tid >> 2, ac = (tid & 3) << 2;
    const int br = tid >> 4, bc = (tid & 15) << 2;

    float acc[4][4] = {};

    for (int k0 = 0; k0 < 512; k0 += 16) {
        float4 a4;
        if (k0 < 256) {
            a4 = *(const float4*)(in1 + (size_t)bidx * EE + k0 + ac);
        } else {
            a4 = *(const float4*)(in2 + (size_t)(m0 + ar) * EE + (k0 - 256) + ac);
        }
        float4 b4 = *(const float4*)(Wq + (size_t)(k0 + br) * HK + n0 + bc);
        As[ar][ac + 0] = a4.x; As[ar][ac + 1] = a4.y;
        As[ar][ac + 2] = a4.z; As[ar][ac + 3] = a4.w;
        Bs[br][bc + 0] = b4.x; Bs[br][bc + 1] = b4.y;
        Bs[br][bc + 2] = b4.z; Bs[br][bc + 3] = b4.w;
        __syncthreads();
#pragma unroll
        for (int kk = 0; kk < 16; ++kk) {
            float a[4], b[4];
#pragma unroll
            for (int r = 0; r < 4; ++r) a[r] = As[tr * 4 + r][kk];
#pragma unroll
            for (int c = 0; c < 4; ++c) b[c] = Bs[kk][tc * 4 + c];
#pragma unroll
            for (int r = 0; r < 4; ++r)
#pragma unroll
                for (int c = 0; c < 4; ++c) acc[r][c] += a[r] * b[c];
        }
        __syncthreads();
    }

#pragma unroll
    for (int r = 0; r < 4; ++r) {
        const int m = m0 + tr * 4 + r;
        const int g = m & (GG - 1);
        const float t = ct[m];
#pragma unroll
        for (int c = 0; c < 4; ++c) {
            const int n = n0 + tc * 4 + c;
            const int h = n >> 4, k = n & 15;
            Qm[(((size_t)bidx * HH + h) * GG + g) * KD + k] =
                acc[r][c] + t * Wq[(size_t)512 * HK + n];
        }
    }
}

// ---------------------------------------------------------------------------
// Flash-style attention, one thread per (b,h,g). K/V rows are wave-uniform
// -> scalar-cache loads; online softmax in registers; no LDS.
// Q/K/V in head-major [B,H,*,16]; output Att in standard [B*G, 256].
// ---------------------------------------------------------------------------
__global__ __launch_bounds__(256) void attn_v2(const float* __restrict__ Qh,
                                               const float* __restrict__ Kh,
                                               const float* __restrict__ Vh,
                                               const float* __restrict__ mask,
                                               float* __restrict__ Att)
{
    const int t = threadIdx.x;
    const int b = blockIdx.z, h = blockIdx.y;
    const int g = blockIdx.x * 256 + t;

    const float4* q4 = (const float4*)(Qh + (((size_t)(b * HH + h) * GG) + g) * KD);
    float4 qa = q4[0], qb = q4[1], qc = q4[2], qd = q4[3];
    float q[16] = {qa.x, qa.y, qa.z, qa.w, qb.x, qb.y, qb.z, qb.w,
                   qc.x, qc.y, qc.z, qc.w, qd.x, qd.y, qd.z, qd.w};

    const float* Kb = Kh + ((size_t)(b * HH + h) * PP) * KD;   // wave-uniform base
    const float* Vb = Vh + ((size_t)(b * HH + h) * PP) * KD;   // wave-uniform base
    const float* mrow = mask + (size_t)(b * GG + g) * PP;

    float acc[16] = {};
    float mrun = -1e30f, lrun = 0.f;

    for (int p0 = 0; p0 < PP; p0 += 8) {
        float s[8];
#pragma unroll
        for (int i = 0; i < 8; ++i) {
            const float4* kr = (const float4*)(Kb + (size_t)(p0 + i) * KD);
            float4 k0 = kr[0], k1 = kr[1], k2 = kr[2], k3 = kr[3];
            float d = q[0] * k0.x + q[1] * k0.y + q[2] * k0.z + q[3] * k0.w
                    + q[4] * k1.x + q[5] * k1.y + q[6] * k1.z + q[7] * k1.w
                    + q[8] * k2.x + q[9] * k2.y + q[10] * k2.z + q[11] * k2.w
                    + q[12] * k3.x + q[13] * k3.y + q[14] * k3.z + q[15] * k3.w;
            s[i] = d * 0.25f + mrow[p0 + i];
        }
        float mc = s[0];
#pragma unroll
        for (int i = 1; i < 8; ++i) mc = fmaxf(mc, s[i]);
        const float mnew = fmaxf(mrun, mc);
        const float scale = __expf(mrun - mnew);
        lrun *= scale;
#pragma unroll
        for (int k = 0; k < 16; ++k) acc[k] *= scale;
#pragma unroll
        for (int i = 0; i < 8; ++i) {
            const float w = __expf(s[i] - mnew);
            lrun += w;
            const float4* vr = (const float4*)(Vb + (size_t)(p0 + i) * KD);
            float4 v0 = vr[0], v1 = vr[1], v2 = vr[2], v3 = vr[3];
            acc[0] += w * v0.x;  acc[1] += w * v0.y;
            acc[2] += w * v0.z;  acc[3] += w * v0.w;
            acc[4] += w * v1.x;  acc[5] += w * v1.y;
            acc[6] += w * v1.z;  acc[7] += w * v1.w;
            acc[8] += w * v2.x;  acc[9] += w * v2.y;
            acc[10] += w * v2.z; acc[11] += w * v2.w;
            acc[12] += w * v3.x; acc[13] += w * v3.y;
            acc[14] += w * v3.z; acc[15] += w * v3.w;
        }
        mrun = mnew;
    }

    const float inv = 1.f / lrun;
    float* orow = Att + (size_t)(b * GG + g) * HK + h * KD;
    float4 o0 = make_float4(acc[0] * inv, acc[1] * inv, acc[2] * inv, acc[3] * inv);
    float4 o1 = make_float4(acc[4] * inv, acc[5] * inv, acc[6] * inv, acc[7] * inv);
    float4 o2 = make_float4(acc[8] * inv, acc[9] * inv, acc[10] * inv, acc[11] * inv);
    float4 o3 = make_float4(acc[12] * inv, acc[13] * inv, acc[14] * inv, acc[15] * inv);
    ((float4*)orow)[0] = o0; ((float4*)orow)[1] = o1;
    ((float4*)orow)[2] = o2; ((float4*)orow)[3] = o3;
}

// ---------------------------------------------------------------------------
// Pointer head: score2 = mh @ enc^T / 16 -> 10*tanh -> +mask -> softmax.
// One block = (b, 16 g's). 256 threads.
// ---------------------------------------------------------------------------
__global__ __launch_bounds__(256) void pointer_probs(const float* __restrict__ mh,
                                                     const float* __restrict__ enc,
                                                     const float* __restrict__ mask,
                                                     float* __restrict__ out)
{
    __shared__ float sM[16][260];
    __shared__ float sS[16][516];
    const int t = threadIdx.x;
    const int b = blockIdx.y, g0 = blockIdx.x * 16;

    {
        const int r = t >> 4;
#pragma unroll
        for (int i = 0; i < 4; ++i) {
            const int c = ((t & 15) << 2) + (i << 6);
            float4 v = *(const float4*)(mh + (size_t)(b * GG + g0 + r) * EE + c);
            sM[r][c + 0] = v.x; sM[r][c + 1] = v.y;
            sM[r][c + 2] = v.z; sM[r][c + 3] = v.w;
        }
    }
    __syncthreads();

    {
        const int g = t & 15;
        const float4* qr = (const float4*)(&sM[g][0]);
        const float* Eb = enc + (size_t)b * PP * EE;
        for (int i4 = 0; i4 < 8; ++i4) {
            const int pb = (t >> 4) + (i4 << 6);
            const float4* e0 = (const float4*)(Eb + (size_t)(pb +  0) * EE);
            const float4* e1 = (const float4*)(Eb + (size_t)(pb + 16) * EE);
            const float4* e2 = (const float4*)(Eb + (size_t)(pb + 32) * EE);
            const float4* e3 = (const float4*)(Eb + (size_t)(pb + 48) * EE);
            float d0 = 0.f, d1 = 0.f, d2 = 0.f, d3 = 0.f;
#pragma unroll 8
            for (int e4 = 0; e4 < 64; ++e4) {
                const float4 qv = qr[e4];
                const float4 a = e0[e4], bb = e1[e4], cc = e2[e4], dd = e3[e4];
                d0 += qv.x * a.x + qv.y * a.y + qv.z * a.z + qv.w * a.w;
                d1 += qv.x * bb.x + qv.y * bb.y + qv.z * bb.z + qv.w * bb.w;
                d2 += qv.x * cc.x + qv.y * cc.y + qv.z * cc.z + qv.w * cc.w;
                d3 += qv.x * dd.x + qv.y * dd.y + qv.z * dd.z + qv.w * dd.w;
            }
            sS[g][pb +  0] = d0 * 0.0625f;
            sS[g][pb + 16] = d1 * 0.0625f;
            sS[g][pb + 32] = d2 * 0.0625f;
            sS[g][pb + 48] = d3 * 0.0625f;
        }
    }
    __syncthreads();

    const int g = t >> 4, j = t & 15;
    const float* mrow = mask + (size_t)(b * GG + g0 + g) * PP;
    float mx = -1e30f;
#pragma unroll 4
    for (int ii = 0; ii < 32; ++ii) {
        const int p = j + (ii << 4);
        const float s = 10.f * tanhf(sS[g][p]) + mrow[p];
        sS[g][p] = s;
        mx = fmaxf(mx, s);
    }
#pragma unroll
    for (int mbit = 1; mbit < 16; mbit <<= 1) mx = fmaxf(mx, __shfl_xor(mx, mbit));
    float sum = 0.f;
#pragma unroll 4
    for (int ii = 0; ii < 32; ++ii) {
        const int p = j + (ii << 4);
        const float e = __expf(sS[g][p] - mx);
        sS[g][p] = e;
        sum += e;
    }
#pragma unroll
    for (int mbit = 1; mbit < 16; mbit <<= 1) sum += __shfl_xor(sum, mbit);
    const float inv = 1.f / sum;
    float* orow = out + (size_t)(b * GG + g0 + g) * PP;
#pragma unroll 4
    for (int ii = 0; ii < 32; ++ii) {
        const int p = j + (ii << 4);
        orow[p] = sS[g][p] * inv;
    }
}

// ---------------------------------------------------------------------------
extern "C" void kernel_launch(void* const* d_in, const int* in_sizes, int n_in,
                              void* d_out, int out_size, void* d_ws, size_t ws_size,
                              hipStream_t stream)
{
    const float* in1  = (const float*)d_in[0];
    const float* in2  = (const float*)d_in[1];
    const float* ct   = (const float*)d_in[2];
    const float* mask = (const float*)d_in[3];
    const float* enc  = (const float*)d_in[4];
    const float* Wq   = (const float*)d_in[5];
    const float* Wk   = (const float*)d_in[6];
    const float* Wv   = (const float*)d_in[7];
    const float* Wcw  = (const float*)d_in[8];
    const float* Wcb  = (const float*)d_in[9];
    float* out = (float*)d_out;
    float* ws  = (float*)d_ws;

    const size_t SEG = (size_t)BB * GG * HK;  // 8 MB
    float* Kmat = ws;            // head-major [B,H,P,16]
    float* Vmat = ws + SEG;      // head-major [B,H,P,16]
    float* Qmat = ws + 2 * SEG;  // head-major [B,H,G,16]
    float* Att  = ws + 3 * SEG;  // standard [B*G, 256]
    float* mhv  = ws;            // reuse Kmat region

    const dim3 blk(256);
    const int M = BB * GG;

    gemm64_perm<<<dim3(HK / 64, M / 64), blk, 0, stream>>>(enc, Wk, Kmat, M, HK, EE);
    gemm64_perm<<<dim3(HK / 64, M / 64), blk, 0, stream>>>(enc, Wv, Vmat, M, HK, EE);
    qgemm      <<<dim3(HK / 64, M / 64), blk, 0, stream>>>(in1, in2, ct, Wq, Qmat);
    attn_v2    <<<dim3(GG / 256, HH, BB), blk, 0, stream>>>(Qmat, Kmat, Vmat, mask, Att);
    gemm64     <<<dim3(HK / 64, M / 64), blk, 0, stream>>>(Att, Wcw, Wcb, mhv, M, HK, EE);
    pointer_probs<<<dim3(GG / 16, BB), blk, 0, stream>>>(mhv, enc, mask, out);
}

// Round 3
// 374.116 us; speedup vs baseline: 1.6477x; 1.2588x over previous
//
#include <hip/hip_runtime.h>
#include <math.h>

#define BB 16
#define GG 512
#define PP 512
#define EE 256
#define HH 16
#define KD 16
#define HK 256

typedef __bf16 bf16x8 __attribute__((ext_vector_type(8)));
typedef __bf16 bf16x4 __attribute__((ext_vector_type(4)));
typedef float f32x4 __attribute__((ext_vector_type(4)));

// ---------------------------------------------------------------------------
// Projection GEMM with head-major epilogue: C'[b,h,p,k] for K/V so attention
// reads rows with wave-uniform (scalar-cache) loads.
// ---------------------------------------------------------------------------
__global__ __launch_bounds__(256) void gemm64_perm(const float* __restrict__ A,
                                                   const float* __restrict__ Bm,
                                                   float* __restrict__ C,
                                                   int M, int N, int Kd)
{
    __shared__ float As[64][17];
    __shared__ float Bs[16][68];
    const int tid = threadIdx.x;
    const int tr = tid >> 4, tc = tid & 15;
    const int m0 = blockIdx.y * 64, n0 = blockIdx.x * 64;
    const int ar = tid >> 2, ac = (tid & 3) << 2;
    const int br = tid >> 4, bc = (tid & 15) << 2;

    float acc[4][4] = {};

    for (int k0 = 0; k0 < Kd; k0 += 16) {
        float4 a4 = *(const float4*)(A + (size_t)(m0 + ar) * Kd + k0 + ac);
        float4 b4 = *(const float4*)(Bm + (size_t)(k0 + br) * N + n0 + bc);
        As[ar][ac + 0] = a4.x; As[ar][ac + 1] = a4.y;
        As[ar][ac + 2] = a4.z; As[ar][ac + 3] = a4.w;
        Bs[br][bc + 0] = b4.x; Bs[br][bc + 1] = b4.y;
        Bs[br][bc + 2] = b4.z; Bs[br][bc + 3] = b4.w;
        __syncthreads();
#pragma unroll
        for (int kk = 0; kk < 16; ++kk) {
            float a[4], b[4];
#pragma unroll
            for (int r = 0; r < 4; ++r) a[r] = As[tr * 4 + r][kk];
#pragma unroll
            for (int c = 0; c < 4; ++c) b[c] = Bs[kk][tc * 4 + c];
#pragma unroll
            for (int r = 0; r < 4; ++r)
#pragma unroll
                for (int c = 0; c < 4; ++c) acc[r][c] += a[r] * b[c];
        }
        __syncthreads();
    }

#pragma unroll
    for (int r = 0; r < 4; ++r) {
        const int m = m0 + tr * 4 + r;
        const int b = m >> 9, p = m & (PP - 1);
#pragma unroll
        for (int c = 0; c < 4; ++c) {
            const int n = n0 + tc * 4 + c;
            const int h = n >> 4, k = n & 15;
            C[(((size_t)b * HH + h) * PP + p) * KD + k] = acc[r][c];
        }
    }
}

// ---------------------------------------------------------------------------
// Output projection GEMM: C = A @ Wc + b, written as split-bf16 (hi/lo) pair
// for the MFMA pointer head. A is Att [8192,256] fp32.
// ---------------------------------------------------------------------------
__global__ __launch_bounds__(256) void gemm64_bf16out(const float* __restrict__ A,
                                                      const float* __restrict__ Bm,
                                                      const float* __restrict__ bias,
                                                      __bf16* __restrict__ Chi,
                                                      __bf16* __restrict__ Clo,
                                                      int M, int N, int Kd)
{
    __shared__ float As[64][17];
    __shared__ float Bs[16][68];
    const int tid = threadIdx.x;
    const int tr = tid >> 4, tc = tid & 15;
    const int m0 = blockIdx.y * 64, n0 = blockIdx.x * 64;
    const int ar = tid >> 2, ac = (tid & 3) << 2;
    const int br = tid >> 4, bc = (tid & 15) << 2;

    float acc[4][4] = {};

    for (int k0 = 0; k0 < Kd; k0 += 16) {
        float4 a4 = *(const float4*)(A + (size_t)(m0 + ar) * Kd + k0 + ac);
        float4 b4 = *(const float4*)(Bm + (size_t)(k0 + br) * N + n0 + bc);
        As[ar][ac + 0] = a4.x; As[ar][ac + 1] = a4.y;
        As[ar][ac + 2] = a4.z; As[ar][ac + 3] = a4.w;
        Bs[br][bc + 0] = b4.x; Bs[br][bc + 1] = b4.y;
        Bs[br][bc + 2] = b4.z; Bs[br][bc + 3] = b4.w;
        __syncthreads();
#pragma unroll
        for (int kk = 0; kk < 16; ++kk) {
            float a[4], b[4];
#pragma unroll
            for (int r = 0; r < 4; ++r) a[r] = As[tr * 4 + r][kk];
#pragma unroll
            for (int c = 0; c < 4; ++c) b[c] = Bs[kk][tc * 4 + c];
#pragma unroll
            for (int r = 0; r < 4; ++r)
#pragma unroll
                for (int c = 0; c < 4; ++c) acc[r][c] += a[r] * b[c];
        }
        __syncthreads();
    }

#pragma unroll
    for (int r = 0; r < 4; ++r) {
        const int m = m0 + tr * 4 + r;
#pragma unroll
        for (int c = 0; c < 4; ++c) {
            const int n = n0 + tc * 4 + c;
            float v = acc[r][c] + bias[n];
            __bf16 h = (__bf16)v;
            __bf16 l = (__bf16)(v - (float)h);
            Chi[(size_t)m * N + n] = h;
            Clo[(size_t)m * N + n] = l;
        }
    }
}

// ---------------------------------------------------------------------------
// Q projection with head-major epilogue: Q'[b,h,g,k].
// ---------------------------------------------------------------------------
__global__ __launch_bounds__(256) void qgemm(const float* __restrict__ in1,
                                             const float* __restrict__ in2,
                                             const float* __restrict__ ct,
                                             const float* __restrict__ Wq,
                                             float* __restrict__ Qm)
{
    __shared__ float As[64][17];
    __shared__ float Bs[16][68];
    const int tid = threadIdx.x;
    const int tr = tid >> 4, tc = tid & 15;
    const int m0 = blockIdx.y * 64, n0 = blockIdx.x * 64;
    const int bidx = m0 >> 9;
    const int ar = tid >> 2, ac = (tid & 3) << 2;
    const int br = tid >> 4, bc = (tid & 15) << 2;

    float acc[4][4] = {};

    for (int k0 = 0; k0 < 512; k0 += 16) {
        float4 a4;
        if (k0 < 256) {
            a4 = *(const float4*)(in1 + (size_t)bidx * EE + k0 + ac);
        } else {
            a4 = *(const float4*)(in2 + (size_t)(m0 + ar) * EE + (k0 - 256) + ac);
        }
        float4 b4 = *(const float4*)(Wq + (size_t)(k0 + br) * HK + n0 + bc);
        As[ar][ac + 0] = a4.x; As[ar][ac + 1] = a4.y;
        As[ar][ac + 2] = a4.z; As[ar][ac + 3] = a4.w;
        Bs[br][bc + 0] = b4.x; Bs[br][bc + 1] = b4.y;
        Bs[br][bc + 2] = b4.z; Bs[br][bc + 3] = b4.w;
        __syncthreads();
#pragma unroll
        for (int kk = 0; kk < 16; ++kk) {
            float a[4], b[4];
#pragma unroll
            for (int r = 0; r < 4; ++r) a[r] = As[tr * 4 + r][kk];
#pragma unroll
            for (int c = 0; c < 4; ++c) b[c] = Bs[kk][tc * 4 + c];
#pragma unroll
            for (int r = 0; r < 4; ++r)
#pragma unroll
                for (int c = 0; c < 4; ++c) acc[r][c] += a[r] * b[c];
        }
        __syncthreads();
    }

#pragma unroll
    for (int r = 0; r < 4; ++r) {
        const int m = m0 + tr * 4 + r;
        const int g = m & (GG - 1);
        const float t = ct[m];
#pragma unroll
        for (int c = 0; c < 4; ++c) {
            const int n = n0 + tc * 4 + c;
            const int h = n >> 4, k = n & 15;
            Qm[(((size_t)bidx * HH + h) * GG + g) * KD + k] =
                acc[r][c] + t * Wq[(size_t)512 * HK + n];
        }
    }
}

// ---------------------------------------------------------------------------
// Flash-style attention, one thread per (b,h,g); wave-uniform K/V rows.
// ---------------------------------------------------------------------------
__global__ __launch_bounds__(256) void attn_v2(const float* __restrict__ Qh,
                                               const float* __restrict__ Kh,
                                               const float* __restrict__ Vh,
                                               const float* __restrict__ mask,
                                               float* __restrict__ Att)
{
    const int t = threadIdx.x;
    const int b = blockIdx.z, h = blockIdx.y;
    const int g = blockIdx.x * 256 + t;

    const float4* q4 = (const float4*)(Qh + (((size_t)(b * HH + h) * GG) + g) * KD);
    float4 qa = q4[0], qb = q4[1], qc = q4[2], qd = q4[3];
    float q[16] = {qa.x, qa.y, qa.z, qa.w, qb.x, qb.y, qb.z, qb.w,
                   qc.x, qc.y, qc.z, qc.w, qd.x, qd.y, qd.z, qd.w};

    const float* Kb = Kh + ((size_t)(b * HH + h) * PP) * KD;
    const float* Vb = Vh + ((size_t)(b * HH + h) * PP) * KD;
    const float* mrow = mask + (size_t)(b * GG + g) * PP;

    float acc[16] = {};
    float mrun = -1e30f, lrun = 0.f;

    for (int p0 = 0; p0 < PP; p0 += 8) {
        float s[8];
#pragma unroll
        for (int i = 0; i < 8; ++i) {
            const float4* kr = (const float4*)(Kb + (size_t)(p0 + i) * KD);
            float4 k0 = kr[0], k1 = kr[1], k2 = kr[2], k3 = kr[3];
            float d = q[0] * k0.x + q[1] * k0.y + q[2] * k0.z + q[3] * k0.w
                    + q[4] * k1.x + q[5] * k1.y + q[6] * k1.z + q[7] * k1.w
                    + q[8] * k2.x + q[9] * k2.y + q[10] * k2.z + q[11] * k2.w
                    + q[12] * k3.x + q[13] * k3.y + q[14] * k3.z + q[15] * k3.w;
            s[i] = d * 0.25f + mrow[p0 + i];
        }
        float mc = s[0];
#pragma unroll
        for (int i = 1; i < 8; ++i) mc = fmaxf(mc, s[i]);
        const float mnew = fmaxf(mrun, mc);
        const float scale = __expf(mrun - mnew);
        lrun *= scale;
#pragma unroll
        for (int k = 0; k < 16; ++k) acc[k] *= scale;
#pragma unroll
        for (int i = 0; i < 8; ++i) {
            const float w = __expf(s[i] - mnew);
            lrun += w;
            const float4* vr = (const float4*)(Vb + (size_t)(p0 + i) * KD);
            float4 v0 = vr[0], v1 = vr[1], v2 = vr[2], v3 = vr[3];
            acc[0] += w * v0.x;  acc[1] += w * v0.y;
            acc[2] += w * v0.z;  acc[3] += w * v0.w;
            acc[4] += w * v1.x;  acc[5] += w * v1.y;
            acc[6] += w * v1.z;  acc[7] += w * v1.w;
            acc[8] += w * v2.x;  acc[9] += w * v2.y;
            acc[10] += w * v2.z; acc[11] += w * v2.w;
            acc[12] += w * v3.x; acc[13] += w * v3.y;
            acc[14] += w * v3.z; acc[15] += w * v3.w;
        }
        mrun = mnew;
    }

    const float inv = 1.f / lrun;
    float* orow = Att + (size_t)(b * GG + g) * HK + h * KD;
    ((float4*)orow)[0] = make_float4(acc[0] * inv, acc[1] * inv, acc[2] * inv, acc[3] * inv);
    ((float4*)orow)[1] = make_float4(acc[4] * inv, acc[5] * inv, acc[6] * inv, acc[7] * inv);
    ((float4*)orow)[2] = make_float4(acc[8] * inv, acc[9] * inv, acc[10] * inv, acc[11] * inv);
    ((float4*)orow)[3] = make_float4(acc[12] * inv, acc[13] * inv, acc[14] * inv, acc[15] * inv);
}

// ---------------------------------------------------------------------------
// Split fp32 -> (hi, lo) bf16 pair. n must be a multiple of 4.
// ---------------------------------------------------------------------------
__global__ __launch_bounds__(256) void prep_split(const float* __restrict__ src,
                                                  __bf16* __restrict__ hi,
                                                  __bf16* __restrict__ lo)
{
    const int i = (blockIdx.x * 256 + threadIdx.x) * 4;
    float4 v = *(const float4*)(src + i);
    bf16x4 h, l;
    h[0] = (__bf16)v.x; l[0] = (__bf16)(v.x - (float)h[0]);
    h[1] = (__bf16)v.y; l[1] = (__bf16)(v.y - (float)h[1]);
    h[2] = (__bf16)v.z; l[2] = (__bf16)(v.z - (float)h[2]);
    h[3] = (__bf16)v.w; l[3] = (__bf16)(v.w - (float)h[3]);
    *(bf16x4*)(hi + i) = h;
    *(bf16x4*)(lo + i) = l;
}

// ---------------------------------------------------------------------------
// Pointer head via split-bf16 MFMA.
// Per block: 16 g-rows x all 512 p, one batch b. 4 waves, wave w owns
// p in [w*128, w*128+128). NT GEMM: A = mh[16,256], B = enc[b][512,256] (row=p).
// S = A@B^T / 16 -> 10*tanh + mask -> softmax (LDS, 16 lanes/row).
// ---------------------------------------------------------------------------
__global__ __launch_bounds__(256) void pointer_mfma(const __bf16* __restrict__ mh_hi,
                                                    const __bf16* __restrict__ mh_lo,
                                                    const __bf16* __restrict__ enc_hi,
                                                    const __bf16* __restrict__ enc_lo,
                                                    const float* __restrict__ mask,
                                                    float* __restrict__ out)
{
    __shared__ float sS[16][516];
    const int t = threadIdx.x;
    const int b = blockIdx.y, g0 = blockIdx.x * 16;
    const int lane = t & 63, w = t >> 6;
    const int lm = lane & 15;          // A row (m/g) and B row (n/p) within tile
    const int kc = (lane >> 4) * 8;    // k-chunk offset within the 32-wide K step

    const size_t arow = ((size_t)(b * GG + g0 + lm)) * EE + kc;
    const size_t brow = ((size_t)(b * PP + w * 128 + lm)) * EE + kc;

    f32x4 acc[8];
#pragma unroll
    for (int pt = 0; pt < 8; ++pt) acc[pt] = (f32x4){0.f, 0.f, 0.f, 0.f};

    for (int k0 = 0; k0 < EE; k0 += 32) {
        bf16x8 ah = *(const bf16x8*)(mh_hi + arow + k0);
        bf16x8 al = *(const bf16x8*)(mh_lo + arow + k0);
#pragma unroll
        for (int pt = 0; pt < 8; ++pt) {
            const size_t bo = brow + (size_t)pt * 16 * EE + k0;
            bf16x8 bh = *(const bf16x8*)(enc_hi + bo);
            bf16x8 bl = *(const bf16x8*)(enc_lo + bo);
            acc[pt] = __builtin_amdgcn_mfma_f32_16x16x32_bf16(ah, bh, acc[pt], 0, 0, 0);
            acc[pt] = __builtin_amdgcn_mfma_f32_16x16x32_bf16(al, bh, acc[pt], 0, 0, 0);
            acc[pt] = __builtin_amdgcn_mfma_f32_16x16x32_bf16(ah, bl, acc[pt], 0, 0, 0);
        }
    }

    // C/D layout: col = lane&15 (=p within tile), row = (lane>>4)*4 + reg (=g)
    const int rbase = (lane >> 4) * 4;
#pragma unroll
    for (int pt = 0; pt < 8; ++pt) {
        const int p = w * 128 + pt * 16 + lm;
#pragma unroll
        for (int r = 0; r < 4; ++r)
            sS[rbase + r][p] = acc[pt][r] * 0.0625f;  // 1/sqrt(256)
    }
    __syncthreads();

    // clip + mask + softmax + store; 16 lanes per g-row.
    const int g = t >> 4, j = t & 15;
    const float* mrow = mask + (size_t)(b * GG + g0 + g) * PP;
    float mx = -1e30f;
#pragma unroll 4
    for (int ii = 0; ii < 32; ++ii) {
        const int p = j + (ii << 4);
        const float s = 10.f * tanhf(sS[g][p]) + mrow[p];
        sS[g][p] = s;
        mx = fmaxf(mx, s);
    }
#pragma unroll
    for (int mbit = 1; mbit < 16; mbit <<= 1) mx = fmaxf(mx, __shfl_xor(mx, mbit));
    float sum = 0.f;
#pragma unroll 4
    for (int ii = 0; ii < 32; ++ii) {
        const int p = j + (ii << 4);
        const float e = __expf(sS[g][p] - mx);
        sS[g][p] = e;
        sum += e;
    }
#pragma unroll
    for (int mbit = 1; mbit < 16; mbit <<= 1) sum += __shfl_xor(sum, mbit);
    const float inv = 1.f / sum;
    float* orow = out + (size_t)(b * GG + g0 + g) * PP;
#pragma unroll 4
    for (int ii = 0; ii < 32; ++ii) {
        const int p = j + (ii << 4);
        orow[p] = sS[g][p] * inv;
    }
}

// ---------------------------------------------------------------------------
extern "C" void kernel_launch(void* const* d_in, const int* in_sizes, int n_in,
                              void* d_out, int out_size, void* d_ws, size_t ws_size,
                              hipStream_t stream)
{
    const float* in1  = (const float*)d_in[0];
    const float* in2  = (const float*)d_in[1];
    const float* ct   = (const float*)d_in[2];
    const float* mask = (const float*)d_in[3];
    const float* enc  = (const float*)d_in[4];
    const float* Wq   = (const float*)d_in[5];
    const float* Wk   = (const float*)d_in[6];
    const float* Wv   = (const float*)d_in[7];
    const float* Wcw  = (const float*)d_in[8];
    const float* Wcb  = (const float*)d_in[9];
    float* out = (float*)d_out;
    float* ws  = (float*)d_ws;

    const size_t SEG = (size_t)BB * GG * HK;  // 2M floats = 8 MB
    float* Kmat = ws;            // head-major [B,H,P,16]; freed after attn
    float* Vmat = ws + SEG;      // head-major [B,H,P,16]; freed after attn
    float* Qmat = ws + 2 * SEG;  // head-major [B,H,G,16]
    float* Att  = ws + 3 * SEG;  // standard [B*G, 256]
    // overlays (used only after attn_v2):
    __bf16* mh_hi  = (__bf16*)Kmat;            // 4 MB
    __bf16* mh_lo  = mh_hi + SEG;              // 4 MB (SEG bf16 elements)
    __bf16* enc_hi = (__bf16*)Vmat;            // 4 MB
    __bf16* enc_lo = enc_hi + SEG;             // 4 MB

    const dim3 blk(256);
    const int M = BB * GG;

    gemm64_perm<<<dim3(HK / 64, M / 64), blk, 0, stream>>>(enc, Wk, Kmat, M, HK, EE);
    gemm64_perm<<<dim3(HK / 64, M / 64), blk, 0, stream>>>(enc, Wv, Vmat, M, HK, EE);
    qgemm      <<<dim3(HK / 64, M / 64), blk, 0, stream>>>(in1, in2, ct, Wq, Qmat);
    attn_v2    <<<dim3(GG / 256, HH, BB), blk, 0, stream>>>(Qmat, Kmat, Vmat, mask, Att);
    // K/V regions now free: build bf16 split inputs for the MFMA pointer head.
    prep_split <<<dim3((BB * PP * EE) / 1024), blk, 0, stream>>>(enc, enc_hi, enc_lo);
    gemm64_bf16out<<<dim3(HK / 64, M / 64), blk, 0, stream>>>(Att, Wcw, Wcb, mh_hi, mh_lo, M, HK, EE);
    pointer_mfma<<<dim3(GG / 16, BB), blk, 0, stream>>>(mh_hi, mh_lo, enc_hi, enc_lo, mask, out);
}